// Round 11
// baseline (1076.153 us; speedup 1.0000x reference)
//
#include <hip/hip_runtime.h>
#include <hip/hip_cooperative_groups.h>

namespace cg = cooperative_groups;

#define D 128
#define NLAYERS 5
#define NTHR 512

using short8  = __attribute__((ext_vector_type(8))) short;
using short4v = __attribute__((ext_vector_type(4))) short;
using floatx4 = __attribute__((ext_vector_type(4))) float;

__device__ __forceinline__ unsigned bf16_rne(float x) {
    unsigned u = __float_as_uint(x);
    return (u + 0x7fffu + ((u >> 16) & 1u)) >> 16;
}
__device__ __forceinline__ float bf16_to_f32(short s) {
    return __uint_as_float(((unsigned)(unsigned short)s) << 16);
}

// One cooperative kernel: CSR build -> gather -> 5 fused GIN layers -> pool -> final.
// 512 threads (8 waves), 48KB LDS -> 3 blocks/CU (24 waves/CU). Single W buffer,
// Wa/Wb restaged per tile (R8 traffic pattern). Dynamic atomic tile queue per layer.
// Per-tile math identical to R8 (absmax 8.0 lineage).
__global__ __launch_bounds__(NTHR, 6) void mega_kernel(
        const int* __restrict__ x, const int* __restrict__ ei,
        const float* __restrict__ emb,
        const float* __restrict__ Wa, const float* __restrict__ ba,
        const float* __restrict__ Wb, const float* __restrict__ bb,
        const float* __restrict__ Wlin, const float* __restrict__ blin,
        float* __restrict__ out,
        short* __restrict__ H0, short* __restrict__ H1,
        float* __restrict__ pooled, int* __restrict__ deg,
        int* __restrict__ offsets, int* __restrict__ cursor,
        int* __restrict__ bsums, int* __restrict__ csr_src,
        short* __restrict__ wt, int n_nodes, int n_edges) {
    __shared__ __align__(16) short zsh[64 * 128];    // 16KB: z tile -> t tile; scan/pool scratch
    __shared__ __align__(16) short wsh[128 * 128];   // 32KB: Wa then Wb (per tile)
    __shared__ int tile_shared;

    cg::grid_group grid = cg::this_grid();
    const int tid  = threadIdx.x;
    const int nblk = gridDim.x;
    const int gtid = blockIdx.x * NTHR + tid;
    const int gsz  = nblk * NTHR;
    const int* esrc = ei;
    const int* edst = ei + n_edges;
    int* tctr = bsums + 2048;          // NLAYERS tile counters (bsums alloc is 4096 ints)

    // ---- phase 0: zero deg/pooled/tctr, W transpose+bf16 ----
    for (int i = gtid; i < n_nodes; i += gsz) deg[i] = 0;
    if (blockIdx.x == 0 && tid < 128) pooled[tid] = 0.f;
    if (blockIdx.x == 0 && tid >= 128 && tid < 128 + NLAYERS) tctr[tid - 128] = 0;
    for (int g = gtid; g < 2 * NLAYERS * D * D; g += gsz) {
        int mat = g >> 14, idx = g & 16383;
        int n = idx >> 7, k = idx & 127;
        const float* W = (mat & 1) ? (Wb + (size_t)(mat >> 1) * D * D)
                                   : (Wa + (size_t)(mat >> 1) * D * D);
        wt[g] = (short)bf16_rne(W[k * D + n]);
    }
    grid.sync();

    // ---- phase 1: degree histogram ----
    for (int e = gtid; e < n_edges; e += gsz) atomicAdd(&deg[edst[e]], 1);
    grid.sync();

    // ---- phase 2: exclusive scan (tiles of 1024 over n_nodes+1 elems) ----
    const int nt = (n_nodes + 1 + 1023) >> 10;     // ~98 tiles << nblk
    int* sred = (int*)zsh;
    if (blockIdx.x < nt) {                          // 2a: per-tile sums
        int i0 = blockIdx.x * 1024 + tid * 2;
        int v0 = (i0 < n_nodes) ? deg[i0] : 0;
        int v1 = (i0 + 1 < n_nodes) ? deg[i0 + 1] : 0;
        sred[tid] = v0 + v1;
        __syncthreads();
        for (int off = 256; off > 0; off >>= 1) {
            if (tid < off) sred[tid] += sred[tid + off];
            __syncthreads();
        }
        if (tid == 0) bsums[blockIdx.x] = sred[0];
    }
    grid.sync();
    if (blockIdx.x == 0) {                          // 2b: scan of tile sums (nt <= 512)
        int v = (tid < nt) ? bsums[tid] : 0;
        sred[tid] = v;
        __syncthreads();
        for (int off = 1; off < NTHR; off <<= 1) {
            int t2 = (tid >= off) ? sred[tid - off] : 0;
            __syncthreads();
            sred[tid] += t2;
            __syncthreads();
        }
        if (tid < nt) bsums[tid] = sred[tid] - v;   // exclusive
    }
    grid.sync();
    if (blockIdx.x < nt) {                          // 2c: final scan + offsets/cursor
        int i0 = blockIdx.x * 1024 + tid * 2;
        int v0 = (i0 < n_nodes) ? deg[i0] : 0;
        int v1 = (i0 + 1 < n_nodes) ? deg[i0 + 1] : 0;
        int s = v0 + v1;
        sred[tid] = s;
        __syncthreads();
        for (int off = 1; off < NTHR; off <<= 1) {
            int t2 = (tid >= off) ? sred[tid - off] : 0;
            __syncthreads();
            sred[tid] += t2;
            __syncthreads();
        }
        int excl = sred[tid] - s + bsums[blockIdx.x];
        if (i0 <= n_nodes) {
            offsets[i0] = excl;
            if (i0 < n_nodes) cursor[i0] = excl;
        }
        int e1 = excl + v0;
        if (i0 + 1 <= n_nodes) {
            offsets[i0 + 1] = e1;
            if (i0 + 1 < n_nodes) cursor[i0 + 1] = e1;
        }
    }
    grid.sync();

    // ---- phase 3: CSR fill + gather H0 = bf16(emb[x]) ----
    for (int e = gtid; e < n_edges; e += gsz) {
        int pos = atomicAdd(&cursor[edst[e]], 1);
        csr_src[pos] = esrc[e];
    }
    for (int t = gtid; t < n_nodes * 32; t += gsz) {
        int node = t >> 5, lane = t & 31;
        int s = x[node];
        const float4 v = *reinterpret_cast<const float4*>(emb + (size_t)s * D + lane * 4);
        short4v o;
        o[0] = (short)bf16_rne(v.x); o[1] = (short)bf16_rne(v.y);
        o[2] = (short)bf16_rne(v.z); o[3] = (short)bf16_rne(v.w);
        *reinterpret_cast<short4v*>(H0 + (size_t)node * D + lane * 4) = o;
    }
    grid.sync();

    // ---- phase 4: 5 fused layers, 64-row tiles, dynamic queue ----
    const int ntiles = (n_nodes + 63) >> 6;
    const int lane = tid & 63;
    const int wave = tid >> 6;      // 0..7
    const int wr   = wave >> 1;     // 16-row group (0..3)
    const int wc   = wave & 1;      // 64-col group
    const int lm   = lane & 15;
    const int quad = lane >> 4;

    for (int l = 0; l < NLAYERS; l++) {
        const short* h_in  = (l & 1) ? H1 : H0;
        short*       h_out = (l & 1) ? H0 : H1;
        const short* wta = wt + (size_t)(2 * l) * D * D;
        const short* wtb = wta + D * D;
        const float* bal = ba + l * D;
        const float* bbl = bb + l * D;

        for (;;) {
            __syncthreads();                 // prev tile's wsh/zsh reads complete
            if (tid == 0) tile_shared = atomicAdd(&tctr[l], 1);
            __syncthreads();
            const int t = tile_shared;
            if (t >= ntiles) break;
            const int row0 = t << 6;

            // stage Wa (2048 chunks over 512 threads)
            #pragma unroll
            for (int i = 0; i < 4; i++) {
                int g = i * NTHR + tid;
                int n = g >> 4, c = g & 15;
                *reinterpret_cast<short8*>(&wsh[(n * 16 + (c ^ (n & 15))) * 8]) =
                    *reinterpret_cast<const short8*>(wta + n * D + c * 8);
            }

            // aggregation: row r = tid>>3, lane l8 = tid&7 owns 32B; 4-way edge unroll (R8)
            {
                const int r  = tid >> 3;
                const int l8 = tid & 7;
                const int gr = row0 + r;
                float acc[16];
                if (gr < n_nodes) {
                    const size_t cb = (size_t)gr * D + l8 * 16;
                    short8 s0 = *reinterpret_cast<const short8*>(h_in + cb);
                    short8 s1 = *reinterpret_cast<const short8*>(h_in + cb + 8);
                    #pragma unroll
                    for (int j = 0; j < 8; j++) { acc[j] = bf16_to_f32(s0[j]); acc[8 + j] = bf16_to_f32(s1[j]); }
                    int beg = offsets[gr];
                    int end = offsets[gr + 1];
                    int e = beg;
                    for (; e + 3 < end; e += 4) {
                        int sA = csr_src[e];
                        int sB = csr_src[e + 1];
                        int sC = csr_src[e + 2];
                        int sD = csr_src[e + 3];
                        const short* pA = h_in + (size_t)sA * D + l8 * 16;
                        const short* pB = h_in + (size_t)sB * D + l8 * 16;
                        const short* pC = h_in + (size_t)sC * D + l8 * 16;
                        const short* pD = h_in + (size_t)sD * D + l8 * 16;
                        short8 a0 = *reinterpret_cast<const short8*>(pA);
                        short8 a1 = *reinterpret_cast<const short8*>(pA + 8);
                        short8 b0 = *reinterpret_cast<const short8*>(pB);
                        short8 b1 = *reinterpret_cast<const short8*>(pB + 8);
                        short8 c0 = *reinterpret_cast<const short8*>(pC);
                        short8 c1 = *reinterpret_cast<const short8*>(pC + 8);
                        short8 d0 = *reinterpret_cast<const short8*>(pD);
                        short8 d1 = *reinterpret_cast<const short8*>(pD + 8);
                        #pragma unroll
                        for (int j = 0; j < 8; j++) {
                            acc[j]     += (bf16_to_f32(a0[j]) + bf16_to_f32(b0[j]))
                                        + (bf16_to_f32(c0[j]) + bf16_to_f32(d0[j]));
                            acc[8 + j] += (bf16_to_f32(a1[j]) + bf16_to_f32(b1[j]))
                                        + (bf16_to_f32(c1[j]) + bf16_to_f32(d1[j]));
                        }
                    }
                    for (; e < end; e++) {
                        int sA = csr_src[e];
                        const short* pA = h_in + (size_t)sA * D + l8 * 16;
                        short8 a0 = *reinterpret_cast<const short8*>(pA);
                        short8 a1 = *reinterpret_cast<const short8*>(pA + 8);
                        #pragma unroll
                        for (int j = 0; j < 8; j++) {
                            acc[j]     += bf16_to_f32(a0[j]);
                            acc[8 + j] += bf16_to_f32(a1[j]);
                        }
                    }
                } else {
                    #pragma unroll
                    for (int j = 0; j < 16; j++) acc[j] = 0.f;
                }
                short8 o0, o1;
                #pragma unroll
                for (int j = 0; j < 8; j++) { o0[j] = (short)bf16_rne(acc[j]); o1[j] = (short)bf16_rne(acc[8 + j]); }
                const int c0i = 2 * l8, c1i = 2 * l8 + 1;
                *reinterpret_cast<short8*>(&zsh[(r * 16 + (c0i ^ (r & 15))) * 8]) = o0;
                *reinterpret_cast<short8*>(&zsh[(r * 16 + (c1i ^ (r & 15))) * 8]) = o1;
            }
            __syncthreads();

            // GEMM1: t = relu(z @ Wa + ba)
            floatx4 acc1[4];
            #pragma unroll
            for (int b = 0; b < 4; b++) acc1[b] = floatx4{0.f, 0.f, 0.f, 0.f};
            {
                const int r = wr * 16 + lm;
                #pragma unroll
                for (int ks = 0; ks < 4; ks++) {
                    const int c = ks * 4 + quad;
                    short8 av = *reinterpret_cast<const short8*>(&zsh[(r * 16 + (c ^ (r & 15))) * 8]);
                    #pragma unroll
                    for (int cs = 0; cs < 4; cs++) {
                        int nn = wc * 64 + cs * 16 + lm;
                        short8 bv = *reinterpret_cast<const short8*>(&wsh[(nn * 16 + (c ^ (nn & 15))) * 8]);
                        acc1[cs] = __builtin_amdgcn_mfma_f32_16x16x32_bf16(av, bv, acc1[cs], 0, 0, 0);
                    }
                }
            }
            __syncthreads();   // wsh (Wa) and zsh (z) reads complete

            // stage Wb + epilogue1 (t -> zsh)
            #pragma unroll
            for (int i = 0; i < 4; i++) {
                int g = i * NTHR + tid;
                int n = g >> 4, c = g & 15;
                *reinterpret_cast<short8*>(&wsh[(n * 16 + (c ^ (n & 15))) * 8]) =
                    *reinterpret_cast<const short8*>(wtb + n * D + c * 8);
            }
            #pragma unroll
            for (int cs = 0; cs < 4; cs++) {
                int col = wc * 64 + cs * 16 + lm;
                float bva = bal[col];
                int cj = col >> 3, ci = col & 7;
                #pragma unroll
                for (int reg = 0; reg < 4; reg++) {
                    int r = wr * 16 + quad * 4 + reg;
                    float v = fmaxf(acc1[cs][reg] + bva, 0.f);
                    zsh[(r * 16 + (cj ^ (r & 15))) * 8 + ci] = (short)bf16_rne(v);
                }
            }
            __syncthreads();

            // GEMM2: h = relu(t @ Wb + bb)
            floatx4 acc2[4];
            #pragma unroll
            for (int b = 0; b < 4; b++) acc2[b] = floatx4{0.f, 0.f, 0.f, 0.f};
            {
                const int r = wr * 16 + lm;
                #pragma unroll
                for (int ks = 0; ks < 4; ks++) {
                    const int c = ks * 4 + quad;
                    short8 av = *reinterpret_cast<const short8*>(&zsh[(r * 16 + (c ^ (r & 15))) * 8]);
                    #pragma unroll
                    for (int cs = 0; cs < 4; cs++) {
                        int nn = wc * 64 + cs * 16 + lm;
                        short8 bv = *reinterpret_cast<const short8*>(&wsh[(nn * 16 + (c ^ (nn & 15))) * 8]);
                        acc2[cs] = __builtin_amdgcn_mfma_f32_16x16x32_bf16(av, bv, acc2[cs], 0, 0, 0);
                    }
                }
            }

            // epilogue2 -> global
            #pragma unroll
            for (int cs = 0; cs < 4; cs++) {
                int col = wc * 64 + cs * 16 + lm;
                float bvb = bbl[col];
                #pragma unroll
                for (int reg = 0; reg < 4; reg++) {
                    int r = row0 + wr * 16 + quad * 4 + reg;
                    if (r < n_nodes) {
                        float v = fmaxf(acc2[cs][reg] + bvb, 0.f);
                        h_out[(size_t)r * D + col] = (short)bf16_rne(v);
                    }
                }
            }
        }
        grid.sync();
    }

    // ---- phase 5: pool (final h is H1, NLAYERS odd) ----
    {
        const short* hf = H1;
        float* red = (float*)zsh;            // [32][128] floats = 16KB
        const int c8 = tid & 15;
        const int rg = tid >> 4;             // 0..31
        for (int r0 = blockIdx.x * 512; r0 < n_nodes; r0 += nblk * 512) {
            int rend = min(r0 + 512, n_nodes);
            float acc[8];
            #pragma unroll
            for (int j = 0; j < 8; j++) acc[j] = 0.f;
            for (int r = r0 + rg; r < rend; r += 32) {
                short8 v = *reinterpret_cast<const short8*>(hf + (size_t)r * D + c8 * 8);
                #pragma unroll
                for (int j = 0; j < 8; j++) acc[j] += bf16_to_f32(v[j]);
            }
            __syncthreads();
            #pragma unroll
            for (int j = 0; j < 8; j++) red[rg * 128 + c8 * 8 + j] = acc[j];
            __syncthreads();
            if (tid < 128) {
                float s = 0.f;
                #pragma unroll
                for (int g = 0; g < 32; g++) s += red[g * 128 + tid];
                atomicAdd(&pooled[tid], s);
            }
            __syncthreads();
        }
    }
    grid.sync();

    // ---- phase 6: final linear (fp32 exact) ----
    if (blockIdx.x == 0) {
        float* p = (float*)zsh;
        if (tid < 128) p[tid] = pooled[tid];
        __syncthreads();
        if (tid < 128) {
            float s = blin[tid];
            #pragma unroll 8
            for (int k = 0; k < D; k++) s += p[k] * Wlin[k * D + tid];
            out[tid] = s;
        }
    }
}

extern "C" void kernel_launch(void* const* d_in, const int* in_sizes, int n_in,
                              void* d_out, int out_size, void* d_ws, size_t ws_size,
                              hipStream_t stream) {
    const int*   x    = (const int*)d_in[0];
    const int*   ei   = (const int*)d_in[1];
    const float* emb  = (const float*)d_in[2];
    const float* Wa   = (const float*)d_in[3];
    const float* ba   = (const float*)d_in[4];
    const float* Wb   = (const float*)d_in[5];
    const float* bb   = (const float*)d_in[6];
    const float* Wlin = (const float*)d_in[7];
    const float* blin = (const float*)d_in[8];
    float* out = (float*)d_out;

    int N = in_sizes[0];
    int E = in_sizes[1] / 2;

    // workspace layout: H0 | H1 (bf16) | pooled | deg | offsets | cursor | bsums(+tctr) | csr_src | wt
    short* H0 = (short*)d_ws;                       // N*D
    short* H1 = H0 + (size_t)N * D;                 // N*D
    float* pooled = (float*)(H1 + (size_t)N * D);   // 128
    int* deg     = (int*)(pooled + 128);            // N
    int* offsets = deg + N;                         // N+1
    int* cursor  = offsets + (N + 1);               // N
    int* bsums   = cursor + N;                      // 4096 (scan sums + tile counters)
    int* csr_src = bsums + 4096;                    // E
    uintptr_t wt_addr = ((uintptr_t)(csr_src + E) + 15) & ~(uintptr_t)15;
    short* wt = (short*)wt_addr;                    // [10][128][128] bf16

    // grid size from occupancy so cooperative co-residency can never fail
    int maxActive = 0;
    if (hipOccupancyMaxActiveBlocksPerMultiprocessor(
            &maxActive, (const void*)mega_kernel, NTHR, 0) != hipSuccess || maxActive < 1)
        maxActive = 1;
    int cus = 256;
    int dev = 0;
    hipGetDevice(&dev);
    hipDeviceGetAttribute(&cus, hipDeviceAttributeMultiprocessorCount, dev);
    int nblk = maxActive * cus;
    if (nblk > 2048) nblk = 2048;

    void* args[] = {
        (void*)&x, (void*)&ei, (void*)&emb, (void*)&Wa, (void*)&ba,
        (void*)&Wb, (void*)&bb, (void*)&Wlin, (void*)&blin, (void*)&out,
        (void*)&H0, (void*)&H1, (void*)&pooled, (void*)&deg, (void*)&offsets,
        (void*)&cursor, (void*)&bsums, (void*)&csr_src, (void*)&wt,
        (void*)&N, (void*)&E
    };
    hipLaunchCooperativeKernel((const void*)mega_kernel, dim3(nblk), dim3(NTHR),
                               args, 0, stream);
}

// Round 12
// 1063.746 us; speedup vs baseline: 1.0117x; 1.0117x over previous
//
#include <hip/hip_runtime.h>
#include <hip/hip_cooperative_groups.h>

namespace cg = cooperative_groups;

#define D 128
#define NLAYERS 5
#define PTHR 256     // prep kernel threads

using short8  = __attribute__((ext_vector_type(8))) short;
using short4v = __attribute__((ext_vector_type(4))) short;
using floatx4 = __attribute__((ext_vector_type(4))) float;

__device__ __forceinline__ unsigned bf16_rne(float x) {
    unsigned u = __float_as_uint(x);
    return (u + 0x7fffu + ((u >> 16) & 1u)) >> 16;
}
__device__ __forceinline__ float bf16_to_f32(short s) {
    return __uint_as_float(((unsigned)(unsigned short)s) << 16);
}

// ---------------- cooperative prep: zero+wsplit+gather -> hist -> scan -> fill ----------------
// 256 threads, 1KB LDS, high occupancy. Replaces 8 tiny dispatches (R8 prologue).
__global__ __launch_bounds__(PTHR) void prep_kernel(
        const int* __restrict__ x, const int* __restrict__ ei,
        const float* __restrict__ emb,
        const float* __restrict__ Wa, const float* __restrict__ Wb,
        short* __restrict__ H0, short* __restrict__ wt,
        int* __restrict__ deg, int* __restrict__ offsets,
        int* __restrict__ cursor, int* __restrict__ bsums,
        int* __restrict__ csr_src, int n_nodes, int n_edges) {
    __shared__ int sred[PTHR];
    cg::grid_group grid = cg::this_grid();
    const int tid  = threadIdx.x;
    const int nblk = gridDim.x;
    const int gtid = blockIdx.x * PTHR + tid;
    const int gsz  = nblk * PTHR;
    const int* esrc = ei;
    const int* edst = ei + n_edges;

    // phase 0: zero deg + W transpose/bf16 + gather H0 = bf16(emb[x])  (independent)
    for (int i = gtid; i < n_nodes; i += gsz) deg[i] = 0;
    for (int g = gtid; g < 2 * NLAYERS * D * D; g += gsz) {
        int mat = g >> 14, idx = g & 16383;
        int n = idx >> 7, k = idx & 127;
        const float* W = (mat & 1) ? (Wb + (size_t)(mat >> 1) * D * D)
                                   : (Wa + (size_t)(mat >> 1) * D * D);
        wt[g] = (short)bf16_rne(W[k * D + n]);
    }
    for (int t = gtid; t < n_nodes * 32; t += gsz) {
        int node = t >> 5, lane = t & 31;
        int s = x[node];
        const float4 v = *reinterpret_cast<const float4*>(emb + (size_t)s * D + lane * 4);
        short4v o;
        o[0] = (short)bf16_rne(v.x); o[1] = (short)bf16_rne(v.y);
        o[2] = (short)bf16_rne(v.z); o[3] = (short)bf16_rne(v.w);
        *reinterpret_cast<short4v*>(H0 + (size_t)node * D + lane * 4) = o;
    }
    grid.sync();

    // phase 1: degree histogram
    for (int e = gtid; e < n_edges; e += gsz) atomicAdd(&deg[edst[e]], 1);
    grid.sync();

    // phase 2a: per-tile sums (tile = 1024 elems = 256 thr x 4)
    const int nt = (n_nodes + 1 + 1023) >> 10;   // needs nt <= nblk (98 << 256)
    if (blockIdx.x < nt) {
        int base = blockIdx.x * 1024 + tid * 4;
        int s = 0;
        #pragma unroll
        for (int j = 0; j < 4; j++) {
            int i = base + j;
            if (i < n_nodes) s += deg[i];
        }
        sred[tid] = s;
        __syncthreads();
        for (int off = 128; off > 0; off >>= 1) {
            if (tid < off) sred[tid] += sred[tid + off];
            __syncthreads();
        }
        if (tid == 0) bsums[blockIdx.x] = sred[0];
    }
    grid.sync();

    // phase 2b: block 0 scans tile sums (nt <= 256)
    if (blockIdx.x == 0) {
        int v = (tid < nt) ? bsums[tid] : 0;
        sred[tid] = v;
        __syncthreads();
        for (int off = 1; off < PTHR; off <<= 1) {
            int t2 = (tid >= off) ? sred[tid - off] : 0;
            __syncthreads();
            sred[tid] += t2;
            __syncthreads();
        }
        if (tid < nt) bsums[tid] = sred[tid] - v;   // exclusive
    }
    grid.sync();

    // phase 2c: final scan -> offsets, cursor
    if (blockIdx.x < nt) {
        int base = blockIdx.x * 1024 + tid * 4;
        int v[4];
        int s = 0;
        #pragma unroll
        for (int j = 0; j < 4; j++) {
            int i = base + j;
            v[j] = (i < n_nodes) ? deg[i] : 0;
            s += v[j];
        }
        sred[tid] = s;
        __syncthreads();
        for (int off = 1; off < PTHR; off <<= 1) {
            int t2 = (tid >= off) ? sred[tid - off] : 0;
            __syncthreads();
            sred[tid] += t2;
            __syncthreads();
        }
        int excl = sred[tid] - s + bsums[blockIdx.x];
        #pragma unroll
        for (int j = 0; j < 4; j++) {
            int i = base + j;
            if (i <= n_nodes) offsets[i] = excl;
            if (i < n_nodes) cursor[i] = excl;
            excl += v[j];
        }
    }
    grid.sync();

    // phase 3: CSR fill
    for (int e = gtid; e < n_edges; e += gsz) {
        int pos = atomicAdd(&cursor[edst[e]], 1);
        csr_src[pos] = esrc[e];
    }
}

// ---------------- fused layer (EXACT R8): H_out = relu(relu((H+agg)@Wa+ba)@Wb+bb) ----------------
// block: 64 nodes, 512 threads (8 waves). Node-parallel aggregation, 8 lanes/node x 32B/lane,
// 4-way edge unroll. LDS: zsh 16KB + wa 32KB + wb 32KB = 80KB -> 2 blocks/CU.
// 16B chunks XOR-swizzled: chunk c of row r at (c ^ (r&15)).
__global__ __launch_bounds__(512, 4) void layer_kernel(
        const int* __restrict__ offsets, const int* __restrict__ csr_src,
        const short* __restrict__ h_in, const short* __restrict__ wta,
        const short* __restrict__ wtb, const float* __restrict__ ba,
        const float* __restrict__ bb, short* __restrict__ h_out, int n_rows) {
    __shared__ __align__(16) short zsh[64 * 128];     // z tile, then t tile
    __shared__ __align__(16) short wa[128 * 128];
    __shared__ __align__(16) short wb[128 * 128];

    const int tid  = threadIdx.x;
    const int row0 = blockIdx.x * 64;

    #pragma unroll
    for (int i = 0; i < 4; i++) {
        int g = i * 512 + tid;
        int n = g >> 4, c = g & 15;
        int off = (n * 16 + (c ^ (n & 15))) * 8;
        *reinterpret_cast<short8*>(&wa[off]) =
            *reinterpret_cast<const short8*>(wta + n * D + c * 8);
        *reinterpret_cast<short8*>(&wb[off]) =
            *reinterpret_cast<const short8*>(wtb + n * D + c * 8);
    }

    {
        const int r  = tid >> 3;
        const int l8 = tid & 7;
        const int gr = row0 + r;
        float acc[16];
        if (gr < n_rows) {
            const size_t cb = (size_t)gr * D + l8 * 16;
            short8 s0 = *reinterpret_cast<const short8*>(h_in + cb);
            short8 s1 = *reinterpret_cast<const short8*>(h_in + cb + 8);
            #pragma unroll
            for (int j = 0; j < 8; j++) { acc[j] = bf16_to_f32(s0[j]); acc[8 + j] = bf16_to_f32(s1[j]); }
            int beg = offsets[gr];
            int end = offsets[gr + 1];
            int e = beg;
            for (; e + 3 < end; e += 4) {
                int sA = csr_src[e];
                int sB = csr_src[e + 1];
                int sC = csr_src[e + 2];
                int sD = csr_src[e + 3];
                const short* pA = h_in + (size_t)sA * D + l8 * 16;
                const short* pB = h_in + (size_t)sB * D + l8 * 16;
                const short* pC = h_in + (size_t)sC * D + l8 * 16;
                const short* pD = h_in + (size_t)sD * D + l8 * 16;
                short8 a0 = *reinterpret_cast<const short8*>(pA);
                short8 a1 = *reinterpret_cast<const short8*>(pA + 8);
                short8 b0 = *reinterpret_cast<const short8*>(pB);
                short8 b1 = *reinterpret_cast<const short8*>(pB + 8);
                short8 c0 = *reinterpret_cast<const short8*>(pC);
                short8 c1 = *reinterpret_cast<const short8*>(pC + 8);
                short8 d0 = *reinterpret_cast<const short8*>(pD);
                short8 d1 = *reinterpret_cast<const short8*>(pD + 8);
                #pragma unroll
                for (int j = 0; j < 8; j++) {
                    acc[j]     += (bf16_to_f32(a0[j]) + bf16_to_f32(b0[j]))
                                + (bf16_to_f32(c0[j]) + bf16_to_f32(d0[j]));
                    acc[8 + j] += (bf16_to_f32(a1[j]) + bf16_to_f32(b1[j]))
                                + (bf16_to_f32(c1[j]) + bf16_to_f32(d1[j]));
                }
            }
            for (; e < end; e++) {
                int sA = csr_src[e];
                const short* pA = h_in + (size_t)sA * D + l8 * 16;
                short8 a0 = *reinterpret_cast<const short8*>(pA);
                short8 a1 = *reinterpret_cast<const short8*>(pA + 8);
                #pragma unroll
                for (int j = 0; j < 8; j++) {
                    acc[j]     += bf16_to_f32(a0[j]);
                    acc[8 + j] += bf16_to_f32(a1[j]);
                }
            }
        } else {
            #pragma unroll
            for (int j = 0; j < 16; j++) acc[j] = 0.f;
        }
        short8 o0, o1;
        #pragma unroll
        for (int j = 0; j < 8; j++) { o0[j] = (short)bf16_rne(acc[j]); o1[j] = (short)bf16_rne(acc[8 + j]); }
        const int c0i = 2 * l8, c1i = 2 * l8 + 1;
        *reinterpret_cast<short8*>(&zsh[(r * 16 + (c0i ^ (r & 15))) * 8]) = o0;
        *reinterpret_cast<short8*>(&zsh[(r * 16 + (c1i ^ (r & 15))) * 8]) = o1;
    }
    __syncthreads();

    const int lane = tid & 63;
    const int wave = tid >> 6;
    const int wr   = wave >> 1;
    const int wc   = wave & 1;
    const int lm   = lane & 15;
    const int quad = lane >> 4;

    floatx4 acc1[4];
    #pragma unroll
    for (int b = 0; b < 4; b++) acc1[b] = floatx4{0.f, 0.f, 0.f, 0.f};
    {
        const int r = wr * 16 + lm;
        #pragma unroll
        for (int ks = 0; ks < 4; ks++) {
            const int c = ks * 4 + quad;
            short8 av = *reinterpret_cast<const short8*>(&zsh[(r * 16 + (c ^ (r & 15))) * 8]);
            #pragma unroll
            for (int cs = 0; cs < 4; cs++) {
                int nn = wc * 64 + cs * 16 + lm;
                short8 bv = *reinterpret_cast<const short8*>(&wa[(nn * 16 + (c ^ (nn & 15))) * 8]);
                acc1[cs] = __builtin_amdgcn_mfma_f32_16x16x32_bf16(av, bv, acc1[cs], 0, 0, 0);
            }
        }
    }
    __syncthreads();

    #pragma unroll
    for (int cs = 0; cs < 4; cs++) {
        int col = wc * 64 + cs * 16 + lm;
        float bva = ba[col];
        int cj = col >> 3, ci = col & 7;
        #pragma unroll
        for (int reg = 0; reg < 4; reg++) {
            int r = wr * 16 + quad * 4 + reg;
            float v = fmaxf(acc1[cs][reg] + bva, 0.f);
            zsh[(r * 16 + (cj ^ (r & 15))) * 8 + ci] = (short)bf16_rne(v);
        }
    }
    __syncthreads();

    floatx4 acc2[4];
    #pragma unroll
    for (int b = 0; b < 4; b++) acc2[b] = floatx4{0.f, 0.f, 0.f, 0.f};
    {
        const int r = wr * 16 + lm;
        #pragma unroll
        for (int ks = 0; ks < 4; ks++) {
            const int c = ks * 4 + quad;
            short8 av = *reinterpret_cast<const short8*>(&zsh[(r * 16 + (c ^ (r & 15))) * 8]);
            #pragma unroll
            for (int cs = 0; cs < 4; cs++) {
                int nn = wc * 64 + cs * 16 + lm;
                short8 bv = *reinterpret_cast<const short8*>(&wb[(nn * 16 + (c ^ (nn & 15))) * 8]);
                acc2[cs] = __builtin_amdgcn_mfma_f32_16x16x32_bf16(av, bv, acc2[cs], 0, 0, 0);
            }
        }
    }

    #pragma unroll
    for (int cs = 0; cs < 4; cs++) {
        int col = wc * 64 + cs * 16 + lm;
        float bvb = bb[col];
        #pragma unroll
        for (int reg = 0; reg < 4; reg++) {
            int r = row0 + wr * 16 + quad * 4 + reg;
            if (r < n_rows) {
                float v = fmaxf(acc2[cs][reg] + bvb, 0.f);
                h_out[(size_t)r * D + col] = (short)bf16_rne(v);
            }
        }
    }
}

// ---------------- pooling: per-block partials (no atomics, no zero kernel) ----------------
__global__ void pool_kernel(const short* __restrict__ h, float* __restrict__ ppart, int n_rows) {
    const int c8 = threadIdx.x & 15;
    const int rg = threadIdx.x >> 4;
    const int r0 = blockIdx.x * 256;
    const int rend = min(r0 + 256, n_rows);
    float acc[8];
    #pragma unroll
    for (int j = 0; j < 8; j++) acc[j] = 0.f;
    for (int r = r0 + rg; r < rend; r += 16) {
        short8 v = *reinterpret_cast<const short8*>(h + (size_t)r * D + c8 * 8);
        #pragma unroll
        for (int j = 0; j < 8; j++) acc[j] += bf16_to_f32(v[j]);
    }
    __shared__ float red[16][128];
    #pragma unroll
    for (int j = 0; j < 8; j++) red[rg][c8 * 8 + j] = acc[j];
    __syncthreads();
    if (threadIdx.x < 128) {
        float s = 0.f;
        #pragma unroll
        for (int g = 0; g < 16; g++) s += red[g][threadIdx.x];
        ppart[blockIdx.x * 128 + threadIdx.x] = s;
    }
}

// ---------------- final: reduce partials + linear (fp32 exact) ----------------
__global__ void final_kernel(const float* __restrict__ ppart, int nb,
                             const float* __restrict__ Wlin,
                             const float* __restrict__ blin, float* __restrict__ out) {
    const int j = threadIdx.x;   // 128 threads
    __shared__ float p[D];
    float s = 0.f;
    for (int b = 0; b < nb; b++) s += ppart[b * 128 + j];
    p[j] = s;
    __syncthreads();
    float o = blin[j];
    #pragma unroll 8
    for (int k = 0; k < D; k++) o += p[k] * Wlin[k * D + j];
    out[j] = o;
}

extern "C" void kernel_launch(void* const* d_in, const int* in_sizes, int n_in,
                              void* d_out, int out_size, void* d_ws, size_t ws_size,
                              hipStream_t stream) {
    const int*   x    = (const int*)d_in[0];
    const int*   ei   = (const int*)d_in[1];
    const float* emb  = (const float*)d_in[2];
    const float* Wa   = (const float*)d_in[3];
    const float* ba   = (const float*)d_in[4];
    const float* Wb   = (const float*)d_in[5];
    const float* bb   = (const float*)d_in[6];
    const float* Wlin = (const float*)d_in[7];
    const float* blin = (const float*)d_in[8];
    float* out = (float*)d_out;

    int N = in_sizes[0];
    int E = in_sizes[1] / 2;

    // workspace: H0 | H1 (bf16) | deg | offsets | cursor | bsums | csr_src | ppart | wt
    short* H0 = (short*)d_ws;                       // N*D
    short* H1 = H0 + (size_t)N * D;                 // N*D
    int* deg     = (int*)(H1 + (size_t)N * D);      // N
    int* offsets = deg + N;                         // N+1
    int* cursor  = offsets + (N + 1);               // N
    int* bsums   = cursor + N;                      // 4096
    int* csr_src = bsums + 4096;                    // E
    const int pool_blocks = (N + 255) / 256;
    float* ppart = (float*)(csr_src + E);           // pool_blocks*128
    uintptr_t wt_addr = ((uintptr_t)(ppart + (size_t)pool_blocks * 128) + 15) & ~(uintptr_t)15;
    short* wt = (short*)wt_addr;                    // [10][128][128] bf16

    // cooperative prep grid from occupancy (co-residency guaranteed)
    int maxActive = 0;
    if (hipOccupancyMaxActiveBlocksPerMultiprocessor(
            &maxActive, (const void*)prep_kernel, PTHR, 0) != hipSuccess || maxActive < 1)
        maxActive = 1;
    int cus = 256;
    int dev = 0;
    hipGetDevice(&dev);
    hipDeviceGetAttribute(&cus, hipDeviceAttributeMultiprocessorCount, dev);
    int nblk = maxActive * cus;
    if (nblk > 1024) nblk = 1024;

    void* pargs[] = {
        (void*)&x, (void*)&ei, (void*)&emb, (void*)&Wa, (void*)&Wb,
        (void*)&H0, (void*)&wt, (void*)&deg, (void*)&offsets,
        (void*)&cursor, (void*)&bsums, (void*)&csr_src, (void*)&N, (void*)&E
    };
    hipLaunchCooperativeKernel((const void*)prep_kernel, dim3(nblk), dim3(PTHR),
                               pargs, 0, stream);

    const int layer_blocks = (N + 63) / 64;
    short* hin = H0; short* hout = H1;
    for (int l = 0; l < NLAYERS; l++) {
        layer_kernel<<<layer_blocks, 512, 0, stream>>>(
            offsets, csr_src, hin,
            wt + (size_t)(2 * l) * D * D, wt + (size_t)(2 * l + 1) * D * D,
            ba + (size_t)l * D, bb + (size_t)l * D, hout, N);
        short* tmp = hin; hin = hout; hout = tmp;
    }

    pool_kernel<<<pool_blocks, 256, 0, stream>>>(hin, ppart, N);
    final_kernel<<<1, 128, 0, stream>>>(ppart, pool_blocks, Wlin, blin, out);
}

// Round 13
// 450.451 us; speedup vs baseline: 2.3891x; 2.3615x over previous
//
#include <hip/hip_runtime.h>

#define D 128
#define NLAYERS 5

using short8  = __attribute__((ext_vector_type(8))) short;
using short4v = __attribute__((ext_vector_type(4))) short;
using floatx4 = __attribute__((ext_vector_type(4))) float;

__device__ __forceinline__ unsigned bf16_rne(float x) {
    unsigned u = __float_as_uint(x);
    return (u + 0x7fffu + ((u >> 16) & 1u)) >> 16;
}
__device__ __forceinline__ float bf16_to_f32(short s) {
    return __uint_as_float(((unsigned)(unsigned short)s) << 16);
}

// ---------------- prepA: zero deg/pooled + W transpose/bf16 + gather (independent work) ----------------
__global__ void prepA_kernel(const int* __restrict__ x, const float* __restrict__ emb,
                             const float* __restrict__ Wa, const float* __restrict__ Wb,
                             short* __restrict__ H0, short* __restrict__ wt,
                             int* __restrict__ deg, float* __restrict__ pooled,
                             int n_nodes) {
    const int gtid = blockIdx.x * 256 + threadIdx.x;
    const int gsz  = gridDim.x * 256;
    for (int i = gtid; i < n_nodes; i += gsz) deg[i] = 0;
    if (gtid < 128) pooled[gtid] = 0.f;
    for (int g = gtid; g < 2 * NLAYERS * D * D; g += gsz) {
        int mat = g >> 14, idx = g & 16383;
        int n = idx >> 7, k = idx & 127;
        const float* W = (mat & 1) ? (Wb + (size_t)(mat >> 1) * D * D)
                                   : (Wa + (size_t)(mat >> 1) * D * D);
        wt[g] = (short)bf16_rne(W[k * D + n]);
    }
    for (int t = gtid; t < n_nodes * 32; t += gsz) {
        int node = t >> 5, lane = t & 31;
        int s = x[node];
        const float4 v = *reinterpret_cast<const float4*>(emb + (size_t)s * D + lane * 4);
        short4v o;
        o[0] = (short)bf16_rne(v.x); o[1] = (short)bf16_rne(v.y);
        o[2] = (short)bf16_rne(v.z); o[3] = (short)bf16_rne(v.w);
        *reinterpret_cast<short4v*>(H0 + (size_t)node * D + lane * 4) = o;
    }
}

// ---------------- CSR build (R8-exact) ----------------
__global__ void hist_kernel(const int* __restrict__ edst, int* __restrict__ deg, int n_edges) {
    int e = blockIdx.x * 256 + threadIdx.x;
    if (e < n_edges) atomicAdd(&deg[edst[e]], 1);
}

#define SCAN_TILE 1024
__global__ void scan_sums_kernel(const int* __restrict__ deg, int* __restrict__ bsums, int n) {
    __shared__ int red[256];
    int base = blockIdx.x * SCAN_TILE + threadIdx.x * 4;
    int s = 0;
    #pragma unroll
    for (int j = 0; j < 4; j++) {
        int i = base + j;
        if (i < n) s += deg[i];
    }
    red[threadIdx.x] = s;
    __syncthreads();
    for (int off = 128; off > 0; off >>= 1) {
        if (threadIdx.x < off) red[threadIdx.x] += red[threadIdx.x + off];
        __syncthreads();
    }
    if (threadIdx.x == 0) bsums[blockIdx.x] = red[0];
}

__global__ void scan_bsums_kernel(int* __restrict__ bsums, int nblocks) {
    __shared__ int sdata[256];
    int carry = 0;
    for (int base = 0; base < nblocks; base += 256) {
        int i = base + threadIdx.x;
        int v = (i < nblocks) ? bsums[i] : 0;
        sdata[threadIdx.x] = v;
        __syncthreads();
        for (int off = 1; off < 256; off <<= 1) {
            int t = (threadIdx.x >= off) ? sdata[threadIdx.x - off] : 0;
            __syncthreads();
            sdata[threadIdx.x] += t;
            __syncthreads();
        }
        int incl = sdata[threadIdx.x];
        if (i < nblocks) bsums[i] = carry + incl - v;
        carry += sdata[255];
        __syncthreads();
    }
}

__global__ void scan_final_kernel(const int* __restrict__ deg, const int* __restrict__ bsums,
                                  int* __restrict__ offsets, int* __restrict__ cursor, int n) {
    __shared__ int sdata[256];
    int base = blockIdx.x * SCAN_TILE + threadIdx.x * 4;
    int v[4];
    int s = 0;
    #pragma unroll
    for (int j = 0; j < 4; j++) {
        int i = base + j;
        v[j] = (i < n) ? deg[i] : 0;
        s += v[j];
    }
    sdata[threadIdx.x] = s;
    __syncthreads();
    for (int off = 1; off < 256; off <<= 1) {
        int t = (threadIdx.x >= off) ? sdata[threadIdx.x - off] : 0;
        __syncthreads();
        sdata[threadIdx.x] += t;
        __syncthreads();
    }
    int excl = sdata[threadIdx.x] - s + bsums[blockIdx.x];
    #pragma unroll
    for (int j = 0; j < 4; j++) {
        int i = base + j;
        if (i <= n) offsets[i] = excl;
        if (i < n) cursor[i] = excl;
        excl += v[j];
    }
}

__global__ void fill_kernel(const int* __restrict__ esrc, const int* __restrict__ edst,
                            int* __restrict__ cursor, int* __restrict__ csr_src, int n_edges) {
    int e = blockIdx.x * 256 + threadIdx.x;
    if (e >= n_edges) return;
    int pos = atomicAdd(&cursor[edst[e]], 1);
    csr_src[pos] = esrc[e];
}

// ---------------- fused layer (R8-exact math) + optional fused pool on last layer ----------------
// block: 64 nodes, 512 threads (8 waves). Node-parallel aggregation, 8 lanes/node x 32B/lane,
// 4-way edge unroll. LDS: zsh 16KB + wa 32KB + wb 32KB = 80KB -> 2 blocks/CU.
// 16B chunks XOR-swizzled: chunk c of row r at (c ^ (r&15)).
__global__ __launch_bounds__(512, 4) void layer_kernel(
        const int* __restrict__ offsets, const int* __restrict__ csr_src,
        const short* __restrict__ h_in, const short* __restrict__ wta,
        const short* __restrict__ wtb, const float* __restrict__ ba,
        const float* __restrict__ bb, short* __restrict__ h_out,
        float* __restrict__ pooled_accum, int n_rows) {
    __shared__ __align__(16) short zsh[64 * 128];     // z tile, then t tile, then pool scratch
    __shared__ __align__(16) short wa[128 * 128];
    __shared__ __align__(16) short wb[128 * 128];

    const int tid  = threadIdx.x;
    const int row0 = blockIdx.x * 64;

    #pragma unroll
    for (int i = 0; i < 4; i++) {
        int g = i * 512 + tid;
        int n = g >> 4, c = g & 15;
        int off = (n * 16 + (c ^ (n & 15))) * 8;
        *reinterpret_cast<short8*>(&wa[off]) =
            *reinterpret_cast<const short8*>(wta + n * D + c * 8);
        *reinterpret_cast<short8*>(&wb[off]) =
            *reinterpret_cast<const short8*>(wtb + n * D + c * 8);
    }

    {
        const int r  = tid >> 3;
        const int l8 = tid & 7;
        const int gr = row0 + r;
        float acc[16];
        if (gr < n_rows) {
            const size_t cb = (size_t)gr * D + l8 * 16;
            short8 s0 = *reinterpret_cast<const short8*>(h_in + cb);
            short8 s1 = *reinterpret_cast<const short8*>(h_in + cb + 8);
            #pragma unroll
            for (int j = 0; j < 8; j++) { acc[j] = bf16_to_f32(s0[j]); acc[8 + j] = bf16_to_f32(s1[j]); }
            int beg = offsets[gr];
            int end = offsets[gr + 1];
            int e = beg;
            for (; e + 3 < end; e += 4) {
                int sA = csr_src[e];
                int sB = csr_src[e + 1];
                int sC = csr_src[e + 2];
                int sD = csr_src[e + 3];
                const short* pA = h_in + (size_t)sA * D + l8 * 16;
                const short* pB = h_in + (size_t)sB * D + l8 * 16;
                const short* pC = h_in + (size_t)sC * D + l8 * 16;
                const short* pD = h_in + (size_t)sD * D + l8 * 16;
                short8 a0 = *reinterpret_cast<const short8*>(pA);
                short8 a1 = *reinterpret_cast<const short8*>(pA + 8);
                short8 b0 = *reinterpret_cast<const short8*>(pB);
                short8 b1 = *reinterpret_cast<const short8*>(pB + 8);
                short8 c0 = *reinterpret_cast<const short8*>(pC);
                short8 c1 = *reinterpret_cast<const short8*>(pC + 8);
                short8 d0 = *reinterpret_cast<const short8*>(pD);
                short8 d1 = *reinterpret_cast<const short8*>(pD + 8);
                #pragma unroll
                for (int j = 0; j < 8; j++) {
                    acc[j]     += (bf16_to_f32(a0[j]) + bf16_to_f32(b0[j]))
                                + (bf16_to_f32(c0[j]) + bf16_to_f32(d0[j]));
                    acc[8 + j] += (bf16_to_f32(a1[j]) + bf16_to_f32(b1[j]))
                                + (bf16_to_f32(c1[j]) + bf16_to_f32(d1[j]));
                }
            }
            for (; e < end; e++) {
                int sA = csr_src[e];
                const short* pA = h_in + (size_t)sA * D + l8 * 16;
                short8 a0 = *reinterpret_cast<const short8*>(pA);
                short8 a1 = *reinterpret_cast<const short8*>(pA + 8);
                #pragma unroll
                for (int j = 0; j < 8; j++) {
                    acc[j]     += bf16_to_f32(a0[j]);
                    acc[8 + j] += bf16_to_f32(a1[j]);
                }
            }
        } else {
            #pragma unroll
            for (int j = 0; j < 16; j++) acc[j] = 0.f;
        }
        short8 o0, o1;
        #pragma unroll
        for (int j = 0; j < 8; j++) { o0[j] = (short)bf16_rne(acc[j]); o1[j] = (short)bf16_rne(acc[8 + j]); }
        const int c0i = 2 * l8, c1i = 2 * l8 + 1;
        *reinterpret_cast<short8*>(&zsh[(r * 16 + (c0i ^ (r & 15))) * 8]) = o0;
        *reinterpret_cast<short8*>(&zsh[(r * 16 + (c1i ^ (r & 15))) * 8]) = o1;
    }
    __syncthreads();

    const int lane = tid & 63;
    const int wave = tid >> 6;
    const int wr   = wave >> 1;
    const int wc   = wave & 1;
    const int lm   = lane & 15;
    const int quad = lane >> 4;

    floatx4 acc1[4];
    #pragma unroll
    for (int b = 0; b < 4; b++) acc1[b] = floatx4{0.f, 0.f, 0.f, 0.f};
    {
        const int r = wr * 16 + lm;
        #pragma unroll
        for (int ks = 0; ks < 4; ks++) {
            const int c = ks * 4 + quad;
            short8 av = *reinterpret_cast<const short8*>(&zsh[(r * 16 + (c ^ (r & 15))) * 8]);
            #pragma unroll
            for (int cs = 0; cs < 4; cs++) {
                int nn = wc * 64 + cs * 16 + lm;
                short8 bv = *reinterpret_cast<const short8*>(&wa[(nn * 16 + (c ^ (nn & 15))) * 8]);
                acc1[cs] = __builtin_amdgcn_mfma_f32_16x16x32_bf16(av, bv, acc1[cs], 0, 0, 0);
            }
        }
    }
    __syncthreads();

    #pragma unroll
    for (int cs = 0; cs < 4; cs++) {
        int col = wc * 64 + cs * 16 + lm;
        float bva = ba[col];
        int cj = col >> 3, ci = col & 7;
        #pragma unroll
        for (int reg = 0; reg < 4; reg++) {
            int r = wr * 16 + quad * 4 + reg;
            float v = fmaxf(acc1[cs][reg] + bva, 0.f);
            zsh[(r * 16 + (cj ^ (r & 15))) * 8 + ci] = (short)bf16_rne(v);
        }
    }
    __syncthreads();

    floatx4 acc2[4];
    #pragma unroll
    for (int b = 0; b < 4; b++) acc2[b] = floatx4{0.f, 0.f, 0.f, 0.f};
    {
        const int r = wr * 16 + lm;
        #pragma unroll
        for (int ks = 0; ks < 4; ks++) {
            const int c = ks * 4 + quad;
            short8 av = *reinterpret_cast<const short8*>(&zsh[(r * 16 + (c ^ (r & 15))) * 8]);
            #pragma unroll
            for (int cs = 0; cs < 4; cs++) {
                int nn = wc * 64 + cs * 16 + lm;
                short8 bv = *reinterpret_cast<const short8*>(&wb[(nn * 16 + (c ^ (nn & 15))) * 8]);
                acc2[cs] = __builtin_amdgcn_mfma_f32_16x16x32_bf16(av, bv, acc2[cs], 0, 0, 0);
            }
        }
    }

    float psum[4];   // per-thread, per-cs column partial (only used on last layer)
    #pragma unroll
    for (int cs = 0; cs < 4; cs++) {
        int col = wc * 64 + cs * 16 + lm;
        float bvb = bb[col];
        float s = 0.f;
        #pragma unroll
        for (int reg = 0; reg < 4; reg++) {
            int r = row0 + wr * 16 + quad * 4 + reg;
            if (r < n_rows) {
                float v = fmaxf(acc2[cs][reg] + bvb, 0.f);
                short hv = (short)bf16_rne(v);
                h_out[(size_t)r * D + col] = hv;
                s += bf16_to_f32(hv);   // pool the rounded stored value (R8 pool semantics)
            }
        }
        psum[cs] = s;
    }

    if (pooled_accum != nullptr) {
        __syncthreads();                 // all gemm2 zsh reads done; reuse zsh as f32 scratch
        float* part = (float*)zsh;       // [16][128] floats = 8KB
        #pragma unroll
        for (int cs = 0; cs < 4; cs++)
            part[(wr * 4 + quad) * 128 + wc * 64 + cs * 16 + lm] = psum[cs];
        __syncthreads();
        if (tid < 128) {
            float s = 0.f;
            #pragma unroll
            for (int g = 0; g < 16; g++) s += part[g * 128 + tid];
            atomicAdd(&pooled_accum[tid], s);
        }
    }
}

// ---------------- final linear (fp32 exact) ----------------
__global__ void final_kernel(const float* __restrict__ pooled, const float* __restrict__ Wlin,
                             const float* __restrict__ blin, float* __restrict__ out) {
    const int j = threadIdx.x;
    __shared__ float p[D];
    p[j] = pooled[j];
    __syncthreads();
    float s = blin[j];
    #pragma unroll 8
    for (int k = 0; k < D; k++) s += p[k] * Wlin[k * D + j];
    out[j] = s;
}

extern "C" void kernel_launch(void* const* d_in, const int* in_sizes, int n_in,
                              void* d_out, int out_size, void* d_ws, size_t ws_size,
                              hipStream_t stream) {
    const int*   x    = (const int*)d_in[0];
    const int*   ei   = (const int*)d_in[1];
    const float* emb  = (const float*)d_in[2];
    const float* Wa   = (const float*)d_in[3];
    const float* ba   = (const float*)d_in[4];
    const float* Wb   = (const float*)d_in[5];
    const float* bb   = (const float*)d_in[6];
    const float* Wlin = (const float*)d_in[7];
    const float* blin = (const float*)d_in[8];
    float* out = (float*)d_out;

    const int N = in_sizes[0];
    const int E = in_sizes[1] / 2;
    const int* esrc = ei;
    const int* edst = ei + E;

    // workspace: H0 | H1 (bf16) | pooled | deg | offsets | cursor | bsums | csr_src | wt
    short* H0 = (short*)d_ws;                       // N*D
    short* H1 = H0 + (size_t)N * D;                 // N*D
    float* pooled = (float*)(H1 + (size_t)N * D);   // 128
    int* deg     = (int*)(pooled + 128);            // N
    int* offsets = deg + N;                         // N+1
    int* cursor  = offsets + (N + 1);               // N
    int* bsums   = cursor + N;                      // 4096
    int* csr_src = bsums + 4096;                    // E
    uintptr_t wt_addr = ((uintptr_t)(csr_src + E) + 15) & ~(uintptr_t)15;
    short* wt = (short*)wt_addr;                    // [10][128][128] bf16

    const int scan_blocks = (N + 1 + SCAN_TILE - 1) / SCAN_TILE;

    prepA_kernel<<<1024, 256, 0, stream>>>(x, emb, Wa, Wb, H0, wt, deg, pooled, N);
    hist_kernel<<<(E + 255) / 256, 256, 0, stream>>>(edst, deg, E);
    scan_sums_kernel<<<scan_blocks, 256, 0, stream>>>(deg, bsums, N);
    scan_bsums_kernel<<<1, 256, 0, stream>>>(bsums, scan_blocks);
    scan_final_kernel<<<scan_blocks, 256, 0, stream>>>(deg, bsums, offsets, cursor, N);
    fill_kernel<<<(E + 255) / 256, 256, 0, stream>>>(esrc, edst, cursor, csr_src, E);

    const int layer_blocks = (N + 63) / 64;
    short* hin = H0; short* hout = H1;
    for (int l = 0; l < NLAYERS; l++) {
        float* pacc = (l == NLAYERS - 1) ? pooled : nullptr;
        layer_kernel<<<layer_blocks, 512, 0, stream>>>(
            offsets, csr_src, hin,
            wt + (size_t)(2 * l) * D * D, wt + (size_t)(2 * l + 1) * D * D,
            ba + (size_t)l * D, bb + (size_t)l * D, hout, pacc, N);
        short* tmp = hin; hin = hout; hout = tmp;
    }

    final_kernel<<<1, 128, 0, stream>>>(pooled, Wlin, blin, out);
}